// Round 8
// baseline (1491.115 us; speedup 1.0000x reference)
//
// Round 7: barrier-free K-loops. A and B MFMA fragments are 16B-contiguous in
// NHWC / [tap][co][ci] layouts -> load them per-lane DIRECTLY from global
// (L1/L2-served), removing all LDS staging + __syncthreads from the K-loop
// (was the latency bound: conv1 74us @ 8.5% Mfma, 4% VALU, 4% HBM).
// Double-buffered fragment regs software-pipeline loads across iterations.
// Epilogue: single LDS round-trip (1 barrier), coalesced uint4 stores.
// Predicted: 919 -> ~580-680us; conv bank-conflicts ~0; MfmaUtil 15-35%.
#include <hip/hip_runtime.h>

typedef unsigned short u16;
typedef __attribute__((ext_vector_type(8))) short bf16x8;   // 8 bf16 (4 VGPRs)
typedef __attribute__((ext_vector_type(4))) float f32x4;

__device__ __forceinline__ float bf2f(u16 v){ return __uint_as_float(((unsigned)v) << 16); }
__device__ __forceinline__ u16 f2bf(float f){
  unsigned u = __float_as_uint(f);
  u += 0x7FFFu + ((u >> 16) & 1u);   // RNE
  return (u16)(u >> 16);
}

constexpr int ilog2c(int v){ return v <= 1 ? 0 : 1 + ilog2c(v / 2); }

// ---------------- weight repacks ----------------
__global__ __launch_bounds__(256) void repack_w1m(const float* __restrict__ src,
                                                  u16* __restrict__ dst){
  int i = blockIdx.x * 256 + threadIdx.x;     // over [64][64]
  if (i < 64 * 64){
    int k  = i & 63, co = i >> 6;
    int kh = k >> 4, kw = (k >> 2) & 3, ci = k & 3;
    float v = (ci < 3) ? src[((co * 3 + ci) * 4 + kh) * 4 + kw] : 0.f;
    dst[i] = f2bf(v);
  }
}
__global__ __launch_bounds__(256) void repack_w_bf(const float* __restrict__ src,
                                                   u16* __restrict__ dst,
                                                   int CI, int CO){
  int i = blockIdx.x * 256 + threadIdx.x;     // linear over src = [co][ci][16]
  if (i < CO * CI * 16){
    int t  = i & 15;
    int r  = i >> 4;
    int ci = r & (CI - 1);
    int co = r / CI;
    dst[((size_t)t * CO + co) * CI + ci] = f2bf(src[i]);
  }
}

// ---------------- img repack: NCHW fp32 (16 imgs) -> [16][258][258][4] bf16 ----------------
__global__ __launch_bounds__(256) void repack_img(const float* __restrict__ img,
                                                  u16* __restrict__ dst){
  int i = blockIdx.x * 256 + threadIdx.x;
  int b  = i >> 16;
  int r  = i & 65535;
  int ih = r >> 8, iw = r & 255;
  float c0 = img[((size_t)b * 3 + 0) * 65536 + r];
  float c1 = img[((size_t)b * 3 + 1) * 65536 + r];
  float c2 = img[((size_t)b * 3 + 2) * 65536 + r];
  ushort4 v = { f2bf(c0), f2bf(c1), f2bf(c2), 0 };
  *(ushort4*)(dst + ((size_t)(b * 258 + ih + 1) * 258 + iw + 1) * 4) = v;
}

// ---------------- halo ring zero ----------------
__global__ __launch_bounds__(256) void halo_zero(u16* __restrict__ buf,
                                                 int B, int H, int W, int C){
  const int C2 = C >> 1;
  const int rowCells = W * C2;
  const int colCells = (H - 2) * C2;
  const int perImg = 2 * rowCells + 2 * colCells;
  int i = blockIdx.x * 256 + threadIdx.x;
  if (i >= B * perImg) return;
  int b = i / perImg, r = i % perImg;
  int h, w, cx;
  if (r < 2 * rowCells){
    h = (r < rowCells) ? 0 : (H - 1);
    int rr = (r < rowCells) ? r : (r - rowCells);
    w = rr / C2; cx = rr % C2;
  } else {
    int rr = r - 2 * rowCells;
    int side = rr / colCells, r2 = rr % colCells;
    h = 1 + r2 / C2; w = side ? (W - 1) : 0; cx = r2 % C2;
  }
  ((unsigned*)buf)[(((size_t)b * H + h) * W + w) * C2 + cx] = 0u;
}

// ---------------- histogram ----------------
__global__ __launch_bounds__(256) void hist_part(const float* __restrict__ img,
                                                 float* __restrict__ raw){
  __shared__ float cnt[16 * 256];
  __shared__ float partial[16 * 17];
  const int tid = threadIdx.x;
  const int bc  = blockIdx.x;
  #pragma unroll
  for (int i = 0; i < 16; i++) cnt[i * 256 + tid] = 0.f;
  __syncthreads();
  const float4* p = (const float4*)(img + (size_t)bc * 65536 + blockIdx.y * 8192);
  #pragma unroll
  for (int it = 0; it < 8; ++it){
    float4 v = p[it * 256 + tid];
    float c[4] = { v.x, v.y, v.z, v.w };
    #pragma unroll
    for (int j = 0; j < 4; j++){
      float x = (c[j] + 1.f) * 0.5f;
      int idx = (int)floorf((x + 1.f) * 8.f);
      idx = min(max(idx, 0), 15);
      float inr = (x >= -1.f && x <= 1.f) ? 1.f : 0.f;
      cnt[idx * 256 + tid] += inr;
    }
  }
  __syncthreads();
  {
    int bin = tid & 15, g = tid >> 4;
    float s = 0.f;
    #pragma unroll
    for (int j = 0; j < 16; j++) s += cnt[bin * 256 + g * 16 + j];
    partial[bin * 17 + g] = s;
  }
  __syncthreads();
  if (tid < 16){
    float t = 0.f;
    #pragma unroll
    for (int g = 0; g < 16; g++) t += partial[tid * 17 + g];
    atomicAdd(raw + bc * 16 + tid, t);
  }
}
__global__ __launch_bounds__(256) void hist_finish(const float* __restrict__ raw,
                                                   float* __restrict__ hist){
  int i = blockIdx.x * 256 + threadIdx.x;
  if (i < 3072){
    const float* r = raw + (i >> 4) * 16;
    float s = 0.f;
    #pragma unroll
    for (int j = 0; j < 16; j++) s += r[j];
    hist[i] = r[i & 15] / (s + 1e-6f);
  }
}

// ---------------- conv1 MFMA, barrier-free K: imgr [16][258][258][4] -> act1 -------------
// GEMM M=262144,N=64,K=64. A-frag k = cc*32+quad*8+j maps to (kh=2cc+(quad>>1),
// kw0=(quad&1)*2, 2px x 4ch) = 16 contiguous bytes of imgr. B loaded direct too.
__global__ __launch_bounds__(256, 2) void conv1_mfma(const u16* __restrict__ in,
                                                     const u16* __restrict__ wm1,  // [64][64]
                                                     const float* __restrict__ bias,
                                                     u16* __restrict__ out){
  __shared__ __align__(16) u16 lds[256 * 72];   // epilogue only (36 KB)
  const int tid  = threadIdx.x;
  const int lane = tid & 63;
  const int w    = tid >> 6;
  const int quad = lane >> 4, l15 = lane & 15;
  const int Mbase = blockIdx.x * 256;

  f32x4 acc[4][4];
  #pragma unroll
  for (int i = 0; i < 4; i++)
    #pragma unroll
    for (int j = 0; j < 4; j++) acc[i][j] = (f32x4){0.f, 0.f, 0.f, 0.f};

  bf16x8 bfr[2][4];
  #pragma unroll
  for (int cc = 0; cc < 2; cc++)
    #pragma unroll
    for (int j = 0; j < 4; j++)
      bfr[cc][j] = *(const bf16x8*)(wm1 + (j * 16 + l15) * 64 + cc * 32 + quad * 8);

  #pragma unroll
  for (int cc = 0; cc < 2; cc++){
    const int kh = cc * 2 + (quad >> 1), kw0 = (quad & 1) * 2;
    bf16x8 af[4];
    #pragma unroll
    for (int i = 0; i < 4; i++){
      int m  = Mbase + w * 64 + i * 16 + l15;
      int b  = m >> 14, rr = m & 16383;
      int oh = rr >> 7, ow = rr & 127;
      af[i] = *(const bf16x8*)(in + ((b * 258 + 2 * oh + kh) * 258 + 2 * ow + kw0) * 4);
    }
    #pragma unroll
    for (int i = 0; i < 4; i++)
      #pragma unroll
      for (int j = 0; j < 4; j++)
        acc[i][j] = __builtin_amdgcn_mfma_f32_16x16x32_bf16(af[i], bfr[cc][j], acc[i][j], 0, 0, 0);
  }

  // epilogue: single LDS pass, 1 barrier, coalesced 16B stores
  float bv[4];
  #pragma unroll
  for (int j = 0; j < 4; j++) bv[j] = bias[j * 16 + l15];
  #pragma unroll
  for (int i = 0; i < 4; i++)
    #pragma unroll
    for (int r = 0; r < 4; r++){
      int row = w * 64 + i * 16 + quad * 4 + r;
      #pragma unroll
      for (int j = 0; j < 4; j++)
        lds[row * 72 + j * 16 + l15] = f2bf(fmaxf(acc[i][j][r] + bv[j], 0.f));
    }
  __syncthreads();
  {
    int m  = Mbase + tid;
    int b  = m >> 14, rr = m & 16383;
    int oh = rr >> 7, ow = rr & 127;
    u16* op = out + ((size_t)(b * 130 + oh + 1) * 130 + ow + 1) * 64;
    const u16* lp = lds + tid * 72;
    #pragma unroll
    for (int u = 0; u < 8; u++)
      *(uint4*)(op + u * 8) = *(const uint4*)(lp + u * 8);
  }
}

// ---------------- generic MFMA conv, barrier-free K-loop ----------------
// A-frag: 8 consecutive ci at output pixel m -> 16B direct global load.
// B-frag: 8 consecutive ci at row n of [tap][co][ci] -> 16B direct global load.
// Double-buffered frag regs; zero __syncthreads until the epilogue.
template<int CI, int CO, int HO, int WO, int OPAD, int WM, int WN, int FM, int FN>
__global__ __launch_bounds__(256, 2) void conv_mfma(const u16* __restrict__ in,
                                                    const u16* __restrict__ wr,
                                                    const float* __restrict__ bias,
                                                    u16* __restrict__ out){
  constexpr int HI  = 2 * HO + 2, WI = 2 * WO + 2;
  constexpr int HOP = HO + 2 * OPAD, WOP = WO + 2 * OPAD;
  constexpr int CC  = CI / 32, LCC = ilog2c(CC), NIT = 16 * CC;
  constexpr int TM  = WM * FM * 16, TN = WN * FN * 16;
  constexpr int EPS = TN + 8;
  constexpr int TPX = 256 / TM, UPT = TN / TPX, U4 = UPT / 8;
  __shared__ __align__(16) u16 lds[TM * EPS];   // epilogue only
  const int tid  = threadIdx.x;
  const int lane = tid & 63;
  const int w    = tid >> 6;
  const int quad = lane >> 4, l15 = lane & 15;
  const int wm = w & (WM - 1), wn = w >> ilog2c(WM);
  const int Mbase = blockIdx.x * TM;
  const int Nbase = blockIdx.y * TN;

  int abase[FM], bbase[FN];
  #pragma unroll
  for (int i = 0; i < FM; i++){
    int m  = Mbase + (wm * FM + i) * 16 + l15;
    int b  = m / (HO * WO), rr = m & (HO * WO - 1);
    int oh = rr / WO, ow = rr & (WO - 1);
    abase[i] = ((b * HI + 2 * oh) * WI + 2 * ow) * CI + quad * 8;
  }
  #pragma unroll
  for (int j = 0; j < FN; j++)
    bbase[j] = (Nbase + (wn * FN + j) * 16 + l15) * CI + quad * 8;

  f32x4 acc[FM][FN];
  #pragma unroll
  for (int i = 0; i < FM; i++)
    #pragma unroll
    for (int j = 0; j < FN; j++) acc[i][j] = (f32x4){0.f, 0.f, 0.f, 0.f};

  bf16x8 af[2][FM], bfr[2][FN];
  auto fetch = [&](int it, int buf){          // buf is always a literal -> static regs
    const int tap = it >> LCC, cc = it & (CC - 1);
    const int ad = ((tap >> 2) * WI + (tap & 3)) * CI + cc * 32;
    const int bd = tap * CO * CI + cc * 32;
    if (buf == 0){
      #pragma unroll
      for (int i = 0; i < FM; i++) af[0][i]  = *(const bf16x8*)(in + abase[i] + ad);
      #pragma unroll
      for (int j = 0; j < FN; j++) bfr[0][j] = *(const bf16x8*)(wr + bbase[j] + bd);
    } else {
      #pragma unroll
      for (int i = 0; i < FM; i++) af[1][i]  = *(const bf16x8*)(in + abase[i] + ad);
      #pragma unroll
      for (int j = 0; j < FN; j++) bfr[1][j] = *(const bf16x8*)(wr + bbase[j] + bd);
    }
  };

  fetch(0, 0);
  #pragma unroll 1
  for (int it = 0; it < NIT; it += 2){        // NIT is even
    fetch(it + 1, 1);
    #pragma unroll
    for (int i = 0; i < FM; i++)
      #pragma unroll
      for (int j = 0; j < FN; j++)
        acc[i][j] = __builtin_amdgcn_mfma_f32_16x16x32_bf16(af[0][i], bfr[0][j], acc[i][j], 0, 0, 0);
    if (it + 2 < NIT) fetch(it + 2, 0);
    #pragma unroll
    for (int i = 0; i < FM; i++)
      #pragma unroll
      for (int j = 0; j < FN; j++)
        acc[i][j] = __builtin_amdgcn_mfma_f32_16x16x32_bf16(af[1][i], bfr[1][j], acc[i][j], 0, 0, 0);
  }

  // epilogue: single LDS pass, 1 barrier, coalesced stores
  float bv[FN];
  #pragma unroll
  for (int j = 0; j < FN; j++) bv[j] = bias[Nbase + (wn * FN + j) * 16 + l15];
  #pragma unroll
  for (int i = 0; i < FM; i++)
    #pragma unroll
    for (int r = 0; r < 4; r++){
      int row = (wm * FM + i) * 16 + quad * 4 + r;
      #pragma unroll
      for (int j = 0; j < FN; j++)
        lds[row * EPS + (wn * FN + j) * 16 + l15] = f2bf(fmaxf(acc[i][j][r] + bv[j], 0.f));
    }
  __syncthreads();
  {
    const int p = tid / TPX, q = tid & (TPX - 1);
    int m  = Mbase + p;
    int b  = m / (HO * WO), rr = m & (HO * WO - 1);
    int oh = rr / WO, ow = rr & (WO - 1);
    u16* op = out + (((size_t)b * HOP + oh + OPAD) * WOP + ow + OPAD) * CO + Nbase + q * UPT;
    const u16* lp = lds + p * EPS + q * UPT;
    #pragma unroll
    for (int u = 0; u < U4; u++)
      *(uint4*)(op + u * 8) = *(const uint4*)(lp + u * 8);
  }
}

// ---------------- pool ----------------
__global__ __launch_bounds__(512) void pool_k(const u16* __restrict__ act4,
                                              float* __restrict__ pooled){
  const int c = threadIdx.x;
  const int b = blockIdx.x;
  const u16* p = act4 + (size_t)b * 256 * 512 + c;
  float s = 0.f;
  for (int i = 0; i < 256; i++) s += bf2f(p[i * 512]);
  pooled[b * 512 + c] = s * (1.f / 256.f);
}

// ---------------- FC head ----------------
__global__ __launch_bounds__(64) void feat_k(const float* __restrict__ pooled,
                                             const float* __restrict__ hist,
                                             const float* __restrict__ wf, const float* __restrict__ bfv,
                                             const float* __restrict__ wh, const float* __restrict__ bh,
                                             const float* __restrict__ wo, const float* __restrict__ bo,
                                             float* __restrict__ cfeat){
  __shared__ float comb[128];
  const int j = threadIdx.x;
  const int b = blockIdx.x;
  const float* pb  = pooled + b * 512;
  const float* wfj = wf + j * 512;
  float s = bfv[j];
  for (int k = 0; k < 512; k++) s += pb[k] * wfj[k];
  comb[j] = s;
  const float* hb  = hist + b * 48;
  const float* whj = wh + j * 48;
  float t = bh[j];
  for (int k = 0; k < 48; k++) t += hb[k] * whj[k];
  comb[64 + j] = t;
  __syncthreads();
  if (j < 3){
    float c = bo[j];
    const float* woj = wo + j * 128;
    for (int k = 0; k < 128; k++) c += comb[k] * woj[k];
    cfeat[b * 3 + j] = c;
  }
}

// ---------------- broadcast ----------------
__global__ __launch_bounds__(256) void bcast_k(const float* __restrict__ cfeat,
                                               float* __restrict__ out){
  size_t i = (size_t)blockIdx.x * 256 + threadIdx.x;
  int bc = (int)(i >> 14);
  float v = cfeat[bc];
  ((float4*)out)[i] = make_float4(v, v, v, v);
}

extern "C" void kernel_launch(void* const* d_in, const int* in_sizes, int n_in,
                              void* d_out, int out_size, void* d_ws, size_t ws_size,
                              hipStream_t stream){
  const float* img = (const float*)d_in[0];
  const float* w1  = (const float*)d_in[1];
  const float* b1  = (const float*)d_in[2];
  const float* w2  = (const float*)d_in[3];
  const float* b2  = (const float*)d_in[4];
  const float* w3  = (const float*)d_in[5];
  const float* b3  = (const float*)d_in[6];
  const float* w4  = (const float*)d_in[7];
  const float* b4  = (const float*)d_in[8];
  const float* wf  = (const float*)d_in[9];
  const float* bfv = (const float*)d_in[10];
  const float* wh  = (const float*)d_in[11];
  const float* bh  = (const float*)d_in[12];
  const float* wo  = (const float*)d_in[13];
  const float* bo  = (const float*)d_in[14];
  float* out = (float*)d_out;
  (void)in_sizes; (void)n_in; (void)out_size; (void)ws_size;

  char* ws = (char*)d_ws;
  size_t off = 0;
  auto alloc = [&](size_t bytes) -> void* {
    void* p = ws + off;
    off += (bytes + 255) & ~(size_t)255;
    return p;
  };
  constexpr int BC = 16;
  const size_t A1c  = (size_t)BC * 130 * 130 * 64 * 2;    // 34.6 MB
  const size_t A2c  = (size_t)BC * 66 * 66 * 128 * 2;     // 17.8 MB
  const size_t A4   = (size_t)64 * 16 * 16 * 512 * 2;     // 16.8 MB

  u16*   slot = (u16*)alloc(A1c);
  u16*   act2 = (u16*)alloc(A2c);
  u16*   imgr = act2;                                     // alias
  u16*   act4 = (u16*)alloc(A4);
  u16*   w1m  = (u16*)  alloc((size_t)64 * 64 * 2);
  u16*   w2r  = (u16*)  alloc((size_t)16 * 128 * 64 * 2);
  u16*   w3r  = (u16*)  alloc((size_t)16 * 256 * 128 * 2);
  u16*   w4r  = (u16*)  alloc((size_t)16 * 512 * 256 * 2);
  float* raw    = (float*)alloc((size_t)192 * 16 * 4);
  float* hist   = (float*)alloc((size_t)192 * 16 * 4);
  float* pooled = (float*)alloc((size_t)64 * 512 * 4);
  float* cfeat  = (float*)alloc((size_t)64 * 3 * 4);

  repack_w1m <<<dim3(16),   256, 0, stream>>>(w1, w1m);
  repack_w_bf<<<dim3(512),  256, 0, stream>>>(w2, w2r, 64, 128);
  repack_w_bf<<<dim3(2048), 256, 0, stream>>>(w3, w3r, 128, 256);
  repack_w_bf<<<dim3(8192), 256, 0, stream>>>(w4, w4r, 256, 512);

  hipMemsetAsync(raw, 0, 192 * 16 * 4, stream);
  hist_part<<<dim3(192, 8), 256, 0, stream>>>(img, raw);
  hist_finish<<<dim3(12), 256, 0, stream>>>(raw, hist);

  const int nH1 = 16 * (2 * 130 * 32 + 128 * 2 * 32);
  const int nH2 = 16 * (2 * 66 * 64 + 64 * 2 * 64);
  const int nH3 = 16 * (2 * 34 * 128 + 32 * 2 * 128);
  const int nHI = 16 * (2 * 258 * 2 + 256 * 2 * 2);

  for (int c = 0; c < 4; ++c){
    const float* img_c  = img  + (size_t)c * BC * 3 * 65536;
    u16*         act4_c = act4 + (size_t)c * BC * 256 * 512;

    halo_zero<<<dim3((nHI + 255) / 256), 256, 0, stream>>>(imgr, 16, 258, 258, 4);
    repack_img<<<dim3(4096), 256, 0, stream>>>(img_c, imgr);
    halo_zero<<<dim3((nH1 + 255) / 256), 256, 0, stream>>>(slot, 16, 130, 130, 64);
    conv1_mfma<<<dim3(1024), 256, 0, stream>>>(imgr, w1m, b1, slot);
    halo_zero<<<dim3((nH2 + 255) / 256), 256, 0, stream>>>(act2, 16, 66, 66, 128);  // imgr dead
    // conv2: M=65536, 64x128 tiles -> 1024 blocks
    conv_mfma<64, 128, 64, 64, 1, 1, 4, 4, 2>
        <<<dim3(1024, 1), 256, 0, stream>>>(slot, w2r, b2, act2);
    halo_zero<<<dim3((nH3 + 255) / 256), 256, 0, stream>>>(slot, 16, 34, 34, 256);  // act1 dead
    // conv3: M=16384, 64x128 tiles -> grid(256,2)=512 blocks
    conv_mfma<128, 256, 32, 32, 1, 1, 4, 4, 2>
        <<<dim3(256, 2), 256, 0, stream>>>(act2, w3r, b3, slot);
    // conv4: M=4096, 64x64 tiles -> grid(64,8)=512 blocks
    conv_mfma<256, 512, 16, 16, 0, 2, 2, 2, 2>
        <<<dim3(64, 8), 256, 0, stream>>>(slot, w4r, b4, act4_c);
  }

  pool_k<<<dim3(64), 512, 0, stream>>>(act4, pooled);
  feat_k<<<dim3(64), 64, 0, stream>>>(pooled, hist, wf, bfv, wh, bh, wo, bo, cfeat);
  bcast_k<<<dim3(12288), 256, 0, stream>>>(cfeat, out);
}

// Round 9
// 1431.118 us; speedup vs baseline: 1.0419x; 1.0419x over previous
//
// Round 9: hybrid. conv1 = round-8 barrier-free (CI=4 -> direct loads ARE
// coalesced). conv2/3/4 = coalesced LDS staging again (round-8 direct loads
// were lane-scattered 128B-1KB -> VMEM request-bound, conv4 119us), now with
// 1-barrier/iter double-buffered LDS, KU-wide slabs (conv2/3 KU=2, conv4 KU=4
// -> 16/32/32 barriers vs round-6's 64/128/256), +8 row pad (2-way max),
// register prefetch, single-pass coalesced epilogue.
// Predicted: 1491 -> ~600-700us; MfmaUtil 20-35% on convs; conflicts ~0.
#include <hip/hip_runtime.h>

typedef unsigned short u16;
typedef __attribute__((ext_vector_type(8))) short bf16x8;   // 8 bf16 (4 VGPRs)
typedef __attribute__((ext_vector_type(4))) float f32x4;

__device__ __forceinline__ float bf2f(u16 v){ return __uint_as_float(((unsigned)v) << 16); }
__device__ __forceinline__ u16 f2bf(float f){
  unsigned u = __float_as_uint(f);
  u += 0x7FFFu + ((u >> 16) & 1u);   // RNE
  return (u16)(u >> 16);
}

constexpr int ilog2c(int v){ return v <= 1 ? 0 : 1 + ilog2c(v / 2); }

// ---------------- weight repacks ----------------
__global__ __launch_bounds__(256) void repack_w1m(const float* __restrict__ src,
                                                  u16* __restrict__ dst){
  int i = blockIdx.x * 256 + threadIdx.x;     // over [64][64]
  if (i < 64 * 64){
    int k  = i & 63, co = i >> 6;
    int kh = k >> 4, kw = (k >> 2) & 3, ci = k & 3;
    float v = (ci < 3) ? src[((co * 3 + ci) * 4 + kh) * 4 + kw] : 0.f;
    dst[i] = f2bf(v);
  }
}
__global__ __launch_bounds__(256) void repack_w_bf(const float* __restrict__ src,
                                                   u16* __restrict__ dst,
                                                   int CI, int CO){
  int i = blockIdx.x * 256 + threadIdx.x;     // linear over src = [co][ci][16]
  if (i < CO * CI * 16){
    int t  = i & 15;
    int r  = i >> 4;
    int ci = r & (CI - 1);
    int co = r / CI;
    dst[((size_t)t * CO + co) * CI + ci] = f2bf(src[i]);
  }
}

// ---------------- img repack: NCHW fp32 (16 imgs) -> [16][258][258][4] bf16 ----------------
__global__ __launch_bounds__(256) void repack_img(const float* __restrict__ img,
                                                  u16* __restrict__ dst){
  int i = blockIdx.x * 256 + threadIdx.x;
  int b  = i >> 16;
  int r  = i & 65535;
  int ih = r >> 8, iw = r & 255;
  float c0 = img[((size_t)b * 3 + 0) * 65536 + r];
  float c1 = img[((size_t)b * 3 + 1) * 65536 + r];
  float c2 = img[((size_t)b * 3 + 2) * 65536 + r];
  ushort4 v = { f2bf(c0), f2bf(c1), f2bf(c2), 0 };
  *(ushort4*)(dst + ((size_t)(b * 258 + ih + 1) * 258 + iw + 1) * 4) = v;
}

// ---------------- halo ring zero ----------------
__global__ __launch_bounds__(256) void halo_zero(u16* __restrict__ buf,
                                                 int B, int H, int W, int C){
  const int C2 = C >> 1;
  const int rowCells = W * C2;
  const int colCells = (H - 2) * C2;
  const int perImg = 2 * rowCells + 2 * colCells;
  int i = blockIdx.x * 256 + threadIdx.x;
  if (i >= B * perImg) return;
  int b = i / perImg, r = i % perImg;
  int h, w, cx;
  if (r < 2 * rowCells){
    h = (r < rowCells) ? 0 : (H - 1);
    int rr = (r < rowCells) ? r : (r - rowCells);
    w = rr / C2; cx = rr % C2;
  } else {
    int rr = r - 2 * rowCells;
    int side = rr / colCells, r2 = rr % colCells;
    h = 1 + r2 / C2; w = side ? (W - 1) : 0; cx = r2 % C2;
  }
  ((unsigned*)buf)[(((size_t)b * H + h) * W + w) * C2 + cx] = 0u;
}

// ---------------- histogram ----------------
__global__ __launch_bounds__(256) void hist_part(const float* __restrict__ img,
                                                 float* __restrict__ raw){
  __shared__ float cnt[16 * 256];
  __shared__ float partial[16 * 17];
  const int tid = threadIdx.x;
  const int bc  = blockIdx.x;
  #pragma unroll
  for (int i = 0; i < 16; i++) cnt[i * 256 + tid] = 0.f;
  __syncthreads();
  const float4* p = (const float4*)(img + (size_t)bc * 65536 + blockIdx.y * 8192);
  #pragma unroll
  for (int it = 0; it < 8; ++it){
    float4 v = p[it * 256 + tid];
    float c[4] = { v.x, v.y, v.z, v.w };
    #pragma unroll
    for (int j = 0; j < 4; j++){
      float x = (c[j] + 1.f) * 0.5f;
      int idx = (int)floorf((x + 1.f) * 8.f);
      idx = min(max(idx, 0), 15);
      float inr = (x >= -1.f && x <= 1.f) ? 1.f : 0.f;
      cnt[idx * 256 + tid] += inr;
    }
  }
  __syncthreads();
  {
    int bin = tid & 15, g = tid >> 4;
    float s = 0.f;
    #pragma unroll
    for (int j = 0; j < 16; j++) s += cnt[bin * 256 + g * 16 + j];
    partial[bin * 17 + g] = s;
  }
  __syncthreads();
  if (tid < 16){
    float t = 0.f;
    #pragma unroll
    for (int g = 0; g < 16; g++) t += partial[tid * 17 + g];
    atomicAdd(raw + bc * 16 + tid, t);
  }
}
__global__ __launch_bounds__(256) void hist_finish(const float* __restrict__ raw,
                                                   float* __restrict__ hist){
  int i = blockIdx.x * 256 + threadIdx.x;
  if (i < 3072){
    const float* r = raw + (i >> 4) * 16;
    float s = 0.f;
    #pragma unroll
    for (int j = 0; j < 16; j++) s += r[j];
    hist[i] = r[i & 15] / (s + 1e-6f);
  }
}

// ---------------- conv1 MFMA, barrier-free K (CI=4 -> direct loads coalesced) -----------
__global__ __launch_bounds__(256, 2) void conv1_mfma(const u16* __restrict__ in,
                                                     const u16* __restrict__ wm1,  // [64][64]
                                                     const float* __restrict__ bias,
                                                     u16* __restrict__ out){
  __shared__ __align__(16) u16 lds[256 * 72];   // epilogue only (36 KB)
  const int tid  = threadIdx.x;
  const int lane = tid & 63;
  const int w    = tid >> 6;
  const int quad = lane >> 4, l15 = lane & 15;
  const int Mbase = blockIdx.x * 256;

  f32x4 acc[4][4];
  #pragma unroll
  for (int i = 0; i < 4; i++)
    #pragma unroll
    for (int j = 0; j < 4; j++) acc[i][j] = (f32x4){0.f, 0.f, 0.f, 0.f};

  bf16x8 bfr[2][4];
  #pragma unroll
  for (int cc = 0; cc < 2; cc++)
    #pragma unroll
    for (int j = 0; j < 4; j++)
      bfr[cc][j] = *(const bf16x8*)(wm1 + (j * 16 + l15) * 64 + cc * 32 + quad * 8);

  #pragma unroll
  for (int cc = 0; cc < 2; cc++){
    const int kh = cc * 2 + (quad >> 1), kw0 = (quad & 1) * 2;
    bf16x8 af[4];
    #pragma unroll
    for (int i = 0; i < 4; i++){
      int m  = Mbase + w * 64 + i * 16 + l15;
      int b  = m >> 14, rr = m & 16383;
      int oh = rr >> 7, ow = rr & 127;
      af[i] = *(const bf16x8*)(in + ((b * 258 + 2 * oh + kh) * 258 + 2 * ow + kw0) * 4);
    }
    #pragma unroll
    for (int i = 0; i < 4; i++)
      #pragma unroll
      for (int j = 0; j < 4; j++)
        acc[i][j] = __builtin_amdgcn_mfma_f32_16x16x32_bf16(af[i], bfr[cc][j], acc[i][j], 0, 0, 0);
  }

  float bv[4];
  #pragma unroll
  for (int j = 0; j < 4; j++) bv[j] = bias[j * 16 + l15];
  #pragma unroll
  for (int i = 0; i < 4; i++)
    #pragma unroll
    for (int r = 0; r < 4; r++){
      int row = w * 64 + i * 16 + quad * 4 + r;
      #pragma unroll
      for (int j = 0; j < 4; j++)
        lds[row * 72 + j * 16 + l15] = f2bf(fmaxf(acc[i][j][r] + bv[j], 0.f));
    }
  __syncthreads();
  {
    int m  = Mbase + tid;
    int b  = m >> 14, rr = m & 16383;
    int oh = rr >> 7, ow = rr & 127;
    u16* op = out + ((size_t)(b * 130 + oh + 1) * 130 + ow + 1) * 64;
    const u16* lp = lds + tid * 72;
    #pragma unroll
    for (int u = 0; u < 8; u++)
      *(uint4*)(op + u * 8) = *(const uint4*)(lp + u * 8);
  }
}

// ---------------- generic MFMA conv: staged LDS, 1 barrier/iter, KU K-slabs -------------
// in: [B][2HO+2][2WO+2][CI] bf16 zero-halo; wr: [16][CO][CI] bf16.
// Double-buffered LDS: at iter `it` compute on buf it&1, store prefetched
// regs into buf (it+1)&1 (last read at it-1, protected by it-1's barrier).
template<int CI, int CO, int HO, int WO, int OPAD, int WM, int WN, int FM, int FN, int KU>
__global__ __launch_bounds__(256, 2) void conv_mfma(const u16* __restrict__ in,
                                                    const u16* __restrict__ wr,
                                                    const float* __restrict__ bias,
                                                    u16* __restrict__ out){
  constexpr int HI  = 2 * HO + 2, WI = 2 * WO + 2;
  constexpr int HOP = HO + 2 * OPAD, WOP = WO + 2 * OPAD;
  constexpr int CC  = CI / 32, LCC = ilog2c(CC);
  constexpr int NIT = 16 * CC / KU;
  constexpr int TM  = WM * FM * 16, TN = WN * FN * 16;
  constexpr int RST = KU * 32 + 8;            // staging row stride (u16): 4R bank spread
  constexpr int BUFSZ = (TM + TN) * RST;      // u16 per buffer
  constexpr int ACH = TM * KU / 64, BCH = TN * KU / 64;   // 16B chunks per thread
  constexpr int EPS = TN + 8;
  constexpr int TPX = 256 / TM, UPT = TN / TPX, U4 = UPT / 8;
  static_assert(TM * EPS <= 2 * BUFSZ, "epilogue fits in staging LDS");
  __shared__ __align__(16) u16 lds[2 * BUFSZ];
  const int tid  = threadIdx.x;
  const int lane = tid & 63;
  const int w    = tid >> 6;
  const int quad = lane >> 4, l15 = lane & 15;
  const int wm = w & (WM - 1), wn = w >> ilog2c(WM);
  const int Mbase = blockIdx.x * TM;
  const int Nbase = blockIdx.y * TN;

  const int srow = tid >> 2;                  // 0..63
  const int sel  = (tid & 3) * 8;             // 16B chunk within a 32-elem slab
  int apix[TM / 64], brow[TN / 64];
  #pragma unroll
  for (int g = 0; g < TM / 64; g++){
    int m  = Mbase + srow + 64 * g;
    int b  = m / (HO * WO), rr = m & (HO * WO - 1);
    int oh = rr / WO, ow = rr & (WO - 1);
    apix[g] = ((b * HI + 2 * oh) * WI + 2 * ow) * CI + sel;
  }
  #pragma unroll
  for (int g = 0; g < TN / 64; g++)
    brow[g] = (Nbase + srow + 64 * g) * CI + sel;

  f32x4 acc[FM][FN];
  #pragma unroll
  for (int i = 0; i < FM; i++)
    #pragma unroll
    for (int j = 0; j < FN; j++) acc[i][j] = (f32x4){0.f, 0.f, 0.f, 0.f};

  uint4 ra[ACH], rb[BCH];
  auto fetch = [&](int it){
    #pragma unroll
    for (int i = 0; i < ACH; i++){
      int g = i / KU, s = i % KU, sl = it * KU + s;
      int tap = sl >> LCC, cc = sl & (CC - 1);
      ra[i] = *(const uint4*)(in + apix[g] + ((tap >> 2) * WI + (tap & 3)) * CI + cc * 32);
    }
    #pragma unroll
    for (int i = 0; i < BCH; i++){
      int g = i / KU, s = i % KU, sl = it * KU + s;
      int tap = sl >> LCC, cc = sl & (CC - 1);
      rb[i] = *(const uint4*)(wr + brow[g] + tap * CO * CI + cc * 32);
    }
  };
  auto store = [&](int buf){
    u16* LA = lds + buf * BUFSZ;
    u16* LB = LA + TM * RST;
    #pragma unroll
    for (int i = 0; i < ACH; i++){
      int g = i / KU, s = i % KU;
      *(uint4*)(LA + (srow + 64 * g) * RST + s * 32 + sel) = ra[i];
    }
    #pragma unroll
    for (int i = 0; i < BCH; i++){
      int g = i / KU, s = i % KU;
      *(uint4*)(LB + (srow + 64 * g) * RST + s * 32 + sel) = rb[i];
    }
  };

  fetch(0);
  store(0);
  __syncthreads();
  #pragma unroll 1
  for (int it = 0; it < NIT; ++it){
    if (it + 1 < NIT) fetch(it + 1);
    const u16* LA = lds + (it & 1) * BUFSZ;
    const u16* LB = LA + TM * RST;
    #pragma unroll
    for (int s = 0; s < KU; s++){
      bf16x8 af[FM], bfr[FN];
      #pragma unroll
      for (int i = 0; i < FM; i++)
        af[i]  = *(const bf16x8*)(LA + ((wm * FM + i) * 16 + l15) * RST + s * 32 + quad * 8);
      #pragma unroll
      for (int j = 0; j < FN; j++)
        bfr[j] = *(const bf16x8*)(LB + ((wn * FN + j) * 16 + l15) * RST + s * 32 + quad * 8);
      #pragma unroll
      for (int i = 0; i < FM; i++)
        #pragma unroll
        for (int j = 0; j < FN; j++)
          acc[i][j] = __builtin_amdgcn_mfma_f32_16x16x32_bf16(af[i], bfr[j], acc[i][j], 0, 0, 0);
    }
    if (it + 1 < NIT) store((it + 1) & 1);
    __syncthreads();
  }

  // epilogue: single LDS pass, 1 barrier, coalesced stores
  float bv[FN];
  #pragma unroll
  for (int j = 0; j < FN; j++) bv[j] = bias[Nbase + (wn * FN + j) * 16 + l15];
  #pragma unroll
  for (int i = 0; i < FM; i++)
    #pragma unroll
    for (int r = 0; r < 4; r++){
      int row = (wm * FM + i) * 16 + quad * 4 + r;
      #pragma unroll
      for (int j = 0; j < FN; j++)
        lds[row * EPS + (wn * FN + j) * 16 + l15] = f2bf(fmaxf(acc[i][j][r] + bv[j], 0.f));
    }
  __syncthreads();
  {
    const int p = tid / TPX, q = tid & (TPX - 1);
    int m  = Mbase + p;
    int b  = m / (HO * WO), rr = m & (HO * WO - 1);
    int oh = rr / WO, ow = rr & (WO - 1);
    u16* op = out + (((size_t)b * HOP + oh + OPAD) * WOP + ow + OPAD) * CO + Nbase + q * UPT;
    const u16* lp = lds + p * EPS + q * UPT;
    #pragma unroll
    for (int u = 0; u < U4; u++)
      *(uint4*)(op + u * 8) = *(const uint4*)(lp + u * 8);
  }
}

// ---------------- pool ----------------
__global__ __launch_bounds__(512) void pool_k(const u16* __restrict__ act4,
                                              float* __restrict__ pooled){
  const int c = threadIdx.x;
  const int b = blockIdx.x;
  const u16* p = act4 + (size_t)b * 256 * 512 + c;
  float s = 0.f;
  for (int i = 0; i < 256; i++) s += bf2f(p[i * 512]);
  pooled[b * 512 + c] = s * (1.f / 256.f);
}

// ---------------- FC head ----------------
__global__ __launch_bounds__(64) void feat_k(const float* __restrict__ pooled,
                                             const float* __restrict__ hist,
                                             const float* __restrict__ wf, const float* __restrict__ bfv,
                                             const float* __restrict__ wh, const float* __restrict__ bh,
                                             const float* __restrict__ wo, const float* __restrict__ bo,
                                             float* __restrict__ cfeat){
  __shared__ float comb[128];
  const int j = threadIdx.x;
  const int b = blockIdx.x;
  const float* pb  = pooled + b * 512;
  const float* wfj = wf + j * 512;
  float s = bfv[j];
  for (int k = 0; k < 512; k++) s += pb[k] * wfj[k];
  comb[j] = s;
  const float* hb  = hist + b * 48;
  const float* whj = wh + j * 48;
  float t = bh[j];
  for (int k = 0; k < 48; k++) t += hb[k] * whj[k];
  comb[64 + j] = t;
  __syncthreads();
  if (j < 3){
    float c = bo[j];
    const float* woj = wo + j * 128;
    for (int k = 0; k < 128; k++) c += comb[k] * woj[k];
    cfeat[b * 3 + j] = c;
  }
}

// ---------------- broadcast ----------------
__global__ __launch_bounds__(256) void bcast_k(const float* __restrict__ cfeat,
                                               float* __restrict__ out){
  size_t i = (size_t)blockIdx.x * 256 + threadIdx.x;
  int bc = (int)(i >> 14);
  float v = cfeat[bc];
  ((float4*)out)[i] = make_float4(v, v, v, v);
}

extern "C" void kernel_launch(void* const* d_in, const int* in_sizes, int n_in,
                              void* d_out, int out_size, void* d_ws, size_t ws_size,
                              hipStream_t stream){
  const float* img = (const float*)d_in[0];
  const float* w1  = (const float*)d_in[1];
  const float* b1  = (const float*)d_in[2];
  const float* w2  = (const float*)d_in[3];
  const float* b2  = (const float*)d_in[4];
  const float* w3  = (const float*)d_in[5];
  const float* b3  = (const float*)d_in[6];
  const float* w4  = (const float*)d_in[7];
  const float* b4  = (const float*)d_in[8];
  const float* wf  = (const float*)d_in[9];
  const float* bfv = (const float*)d_in[10];
  const float* wh  = (const float*)d_in[11];
  const float* bh  = (const float*)d_in[12];
  const float* wo  = (const float*)d_in[13];
  const float* bo  = (const float*)d_in[14];
  float* out = (float*)d_out;
  (void)in_sizes; (void)n_in; (void)out_size; (void)ws_size;

  char* ws = (char*)d_ws;
  size_t off = 0;
  auto alloc = [&](size_t bytes) -> void* {
    void* p = ws + off;
    off += (bytes + 255) & ~(size_t)255;
    return p;
  };
  constexpr int BC = 16;
  const size_t A1c  = (size_t)BC * 130 * 130 * 64 * 2;    // 34.6 MB
  const size_t A2c  = (size_t)BC * 66 * 66 * 128 * 2;     // 17.8 MB
  const size_t A4   = (size_t)64 * 16 * 16 * 512 * 2;     // 16.8 MB

  u16*   slot = (u16*)alloc(A1c);
  u16*   act2 = (u16*)alloc(A2c);
  u16*   imgr = act2;                                     // alias
  u16*   act4 = (u16*)alloc(A4);
  u16*   w1m  = (u16*)  alloc((size_t)64 * 64 * 2);
  u16*   w2r  = (u16*)  alloc((size_t)16 * 128 * 64 * 2);
  u16*   w3r  = (u16*)  alloc((size_t)16 * 256 * 128 * 2);
  u16*   w4r  = (u16*)  alloc((size_t)16 * 512 * 256 * 2);
  float* raw    = (float*)alloc((size_t)192 * 16 * 4);
  float* hist   = (float*)alloc((size_t)192 * 16 * 4);
  float* pooled = (float*)alloc((size_t)64 * 512 * 4);
  float* cfeat  = (float*)alloc((size_t)64 * 3 * 4);

  repack_w1m <<<dim3(16),   256, 0, stream>>>(w1, w1m);
  repack_w_bf<<<dim3(512),  256, 0, stream>>>(w2, w2r, 64, 128);
  repack_w_bf<<<dim3(2048), 256, 0, stream>>>(w3, w3r, 128, 256);
  repack_w_bf<<<dim3(8192), 256, 0, stream>>>(w4, w4r, 256, 512);

  hipMemsetAsync(raw, 0, 192 * 16 * 4, stream);
  hist_part<<<dim3(192, 8), 256, 0, stream>>>(img, raw);
  hist_finish<<<dim3(12), 256, 0, stream>>>(raw, hist);

  const int nH1 = 16 * (2 * 130 * 32 + 128 * 2 * 32);
  const int nH2 = 16 * (2 * 66 * 64 + 64 * 2 * 64);
  const int nH3 = 16 * (2 * 34 * 128 + 32 * 2 * 128);
  const int nHI = 16 * (2 * 258 * 2 + 256 * 2 * 2);

  for (int c = 0; c < 4; ++c){
    const float* img_c  = img  + (size_t)c * BC * 3 * 65536;
    u16*         act4_c = act4 + (size_t)c * BC * 256 * 512;

    halo_zero<<<dim3((nHI + 255) / 256), 256, 0, stream>>>(imgr, 16, 258, 258, 4);
    repack_img<<<dim3(4096), 256, 0, stream>>>(img_c, imgr);
    halo_zero<<<dim3((nH1 + 255) / 256), 256, 0, stream>>>(slot, 16, 130, 130, 64);
    conv1_mfma<<<dim3(1024), 256, 0, stream>>>(imgr, w1m, b1, slot);
    halo_zero<<<dim3((nH2 + 255) / 256), 256, 0, stream>>>(act2, 16, 66, 66, 128);  // imgr dead
    // conv2: M=65536, 64x128 tiles, KU=2 (NIT=16) -> 1024 blocks
    conv_mfma<64, 128, 64, 64, 1, 1, 4, 4, 2, 2>
        <<<dim3(1024, 1), 256, 0, stream>>>(slot, w2r, b2, act2);
    halo_zero<<<dim3((nH3 + 255) / 256), 256, 0, stream>>>(slot, 16, 34, 34, 256);  // act1 dead
    // conv3: M=16384, 64x128 tiles, KU=2 (NIT=32) -> grid(256,2)=512 blocks
    conv_mfma<128, 256, 32, 32, 1, 1, 4, 4, 2, 2>
        <<<dim3(256, 2), 256, 0, stream>>>(act2, w3r, b3, slot);
    // conv4: M=4096, 64x64 tiles, KU=4 (NIT=32) -> grid(64,8)=512 blocks
    conv_mfma<256, 512, 16, 16, 0, 2, 2, 2, 2, 4>
        <<<dim3(64, 8), 256, 0, stream>>>(slot, w4r, b4, act4_c);
  }

  pool_k<<<dim3(64), 512, 0, stream>>>(act4, pooled);
  feat_k<<<dim3(64), 64, 0, stream>>>(pooled, hist, wf, bfv, wh, bh, wo, bo, cfeat);
  bcast_k<<<dim3(12288), 256, 0, stream>>>(cfeat, out);
}

// Round 10
// 1014.421 us; speedup vs baseline: 1.4699x; 1.4108x over previous
//
// Round 10: revert to the measured-best structure (round-6 code, 919us), with
// ONE change: conv1 = barrier-free direct-load MFMA (CI=4 -> per-lane 16B frag
// loads ARE coalesced; K=64, 2 iters, no K-loop barriers). Rounds 8-9's
// KU-slab/double-buffer experiments regressed (conv4 WRITE_SIZE 196MB phantom
// traffic) and are dropped. conv2/3/4 = round-6 conv_mfma verbatim
// (2-barrier K-loop + reg prefetch + multi-pass coalesced epilogue).
// Predicted: ~700-760us; conv1 74->~22us; conv4 WRITE back to ~MB-scale.
#include <hip/hip_runtime.h>

typedef unsigned short u16;
typedef __attribute__((ext_vector_type(8))) short bf16x8;   // 8 bf16 (4 VGPRs)
typedef __attribute__((ext_vector_type(4))) float f32x4;

__device__ __forceinline__ float bf2f(u16 v){ return __uint_as_float(((unsigned)v) << 16); }
__device__ __forceinline__ u16 f2bf(float f){
  unsigned u = __float_as_uint(f);
  u += 0x7FFFu + ((u >> 16) & 1u);   // RNE
  return (u16)(u >> 16);
}

constexpr int ilog2c(int v){ return v <= 1 ? 0 : 1 + ilog2c(v / 2); }

// ---------------- weight repacks ----------------
__global__ __launch_bounds__(256) void repack_w1m(const float* __restrict__ src,
                                                  u16* __restrict__ dst){
  int i = blockIdx.x * 256 + threadIdx.x;     // over [64][64]
  if (i < 64 * 64){
    int k  = i & 63, co = i >> 6;
    int kh = k >> 4, kw = (k >> 2) & 3, ci = k & 3;
    float v = (ci < 3) ? src[((co * 3 + ci) * 4 + kh) * 4 + kw] : 0.f;
    dst[i] = f2bf(v);
  }
}
__global__ __launch_bounds__(256) void repack_w_bf(const float* __restrict__ src,
                                                   u16* __restrict__ dst,
                                                   int CI, int CO){
  int i = blockIdx.x * 256 + threadIdx.x;     // linear over src = [co][ci][16]
  if (i < CO * CI * 16){
    int t  = i & 15;
    int r  = i >> 4;
    int ci = r & (CI - 1);
    int co = r / CI;
    dst[((size_t)t * CO + co) * CI + ci] = f2bf(src[i]);
  }
}

// ---------------- img repack: NCHW fp32 (16 imgs) -> [16][258][258][4] bf16 ----------------
__global__ __launch_bounds__(256) void repack_img(const float* __restrict__ img,
                                                  u16* __restrict__ dst){
  int i = blockIdx.x * 256 + threadIdx.x;
  int b  = i >> 16;
  int r  = i & 65535;
  int ih = r >> 8, iw = r & 255;
  float c0 = img[((size_t)b * 3 + 0) * 65536 + r];
  float c1 = img[((size_t)b * 3 + 1) * 65536 + r];
  float c2 = img[((size_t)b * 3 + 2) * 65536 + r];
  ushort4 v = { f2bf(c0), f2bf(c1), f2bf(c2), 0 };
  *(ushort4*)(dst + ((size_t)(b * 258 + ih + 1) * 258 + iw + 1) * 4) = v;
}

// ---------------- halo ring zero ----------------
__global__ __launch_bounds__(256) void halo_zero(u16* __restrict__ buf,
                                                 int B, int H, int W, int C){
  const int C2 = C >> 1;
  const int rowCells = W * C2;
  const int colCells = (H - 2) * C2;
  const int perImg = 2 * rowCells + 2 * colCells;
  int i = blockIdx.x * 256 + threadIdx.x;
  if (i >= B * perImg) return;
  int b = i / perImg, r = i % perImg;
  int h, w, cx;
  if (r < 2 * rowCells){
    h = (r < rowCells) ? 0 : (H - 1);
    int rr = (r < rowCells) ? r : (r - rowCells);
    w = rr / C2; cx = rr % C2;
  } else {
    int rr = r - 2 * rowCells;
    int side = rr / colCells, r2 = rr % colCells;
    h = 1 + r2 / C2; w = side ? (W - 1) : 0; cx = r2 % C2;
  }
  ((unsigned*)buf)[(((size_t)b * H + h) * W + w) * C2 + cx] = 0u;
}

// ---------------- histogram ----------------
__global__ __launch_bounds__(256) void hist_part(const float* __restrict__ img,
                                                 float* __restrict__ raw){
  __shared__ float cnt[16 * 256];
  __shared__ float partial[16 * 17];
  const int tid = threadIdx.x;
  const int bc  = blockIdx.x;
  #pragma unroll
  for (int i = 0; i < 16; i++) cnt[i * 256 + tid] = 0.f;
  __syncthreads();
  const float4* p = (const float4*)(img + (size_t)bc * 65536 + blockIdx.y * 8192);
  #pragma unroll
  for (int it = 0; it < 8; ++it){
    float4 v = p[it * 256 + tid];
    float c[4] = { v.x, v.y, v.z, v.w };
    #pragma unroll
    for (int j = 0; j < 4; j++){
      float x = (c[j] + 1.f) * 0.5f;
      int idx = (int)floorf((x + 1.f) * 8.f);
      idx = min(max(idx, 0), 15);
      float inr = (x >= -1.f && x <= 1.f) ? 1.f : 0.f;
      cnt[idx * 256 + tid] += inr;
    }
  }
  __syncthreads();
  {
    int bin = tid & 15, g = tid >> 4;
    float s = 0.f;
    #pragma unroll
    for (int j = 0; j < 16; j++) s += cnt[bin * 256 + g * 16 + j];
    partial[bin * 17 + g] = s;
  }
  __syncthreads();
  if (tid < 16){
    float t = 0.f;
    #pragma unroll
    for (int g = 0; g < 16; g++) t += partial[tid * 17 + g];
    atomicAdd(raw + bc * 16 + tid, t);
  }
}
__global__ __launch_bounds__(256) void hist_finish(const float* __restrict__ raw,
                                                   float* __restrict__ hist){
  int i = blockIdx.x * 256 + threadIdx.x;
  if (i < 3072){
    const float* r = raw + (i >> 4) * 16;
    float s = 0.f;
    #pragma unroll
    for (int j = 0; j < 16; j++) s += r[j];
    hist[i] = r[i & 15] / (s + 1e-6f);
  }
}

// ---------------- conv1 MFMA, barrier-free K (CI=4 -> direct loads coalesced) -----------
__global__ __launch_bounds__(256, 2) void conv1_mfma(const u16* __restrict__ in,
                                                     const u16* __restrict__ wm1,  // [64][64]
                                                     const float* __restrict__ bias,
                                                     u16* __restrict__ out){
  __shared__ __align__(16) u16 lds[256 * 72];   // epilogue only (36 KB)
  const int tid  = threadIdx.x;
  const int lane = tid & 63;
  const int w    = tid >> 6;
  const int quad = lane >> 4, l15 = lane & 15;
  const int Mbase = blockIdx.x * 256;

  f32x4 acc[4][4];
  #pragma unroll
  for (int i = 0; i < 4; i++)
    #pragma unroll
    for (int j = 0; j < 4; j++) acc[i][j] = (f32x4){0.f, 0.f, 0.f, 0.f};

  bf16x8 bfr[2][4];
  #pragma unroll
  for (int cc = 0; cc < 2; cc++)
    #pragma unroll
    for (int j = 0; j < 4; j++)
      bfr[cc][j] = *(const bf16x8*)(wm1 + (j * 16 + l15) * 64 + cc * 32 + quad * 8);

  #pragma unroll
  for (int cc = 0; cc < 2; cc++){
    const int kh = cc * 2 + (quad >> 1), kw0 = (quad & 1) * 2;
    bf16x8 af[4];
    #pragma unroll
    for (int i = 0; i < 4; i++){
      int m  = Mbase + w * 64 + i * 16 + l15;
      int b  = m >> 14, rr = m & 16383;
      int oh = rr >> 7, ow = rr & 127;
      af[i] = *(const bf16x8*)(in + ((b * 258 + 2 * oh + kh) * 258 + 2 * ow + kw0) * 4);
    }
    #pragma unroll
    for (int i = 0; i < 4; i++)
      #pragma unroll
      for (int j = 0; j < 4; j++)
        acc[i][j] = __builtin_amdgcn_mfma_f32_16x16x32_bf16(af[i], bfr[cc][j], acc[i][j], 0, 0, 0);
  }

  float bv[4];
  #pragma unroll
  for (int j = 0; j < 4; j++) bv[j] = bias[j * 16 + l15];
  #pragma unroll
  for (int i = 0; i < 4; i++)
    #pragma unroll
    for (int r = 0; r < 4; r++){
      int row = w * 64 + i * 16 + quad * 4 + r;
      #pragma unroll
      for (int j = 0; j < 4; j++)
        lds[row * 72 + j * 16 + l15] = f2bf(fmaxf(acc[i][j][r] + bv[j], 0.f));
    }
  __syncthreads();
  {
    int m  = Mbase + tid;
    int b  = m >> 14, rr = m & 16383;
    int oh = rr >> 7, ow = rr & 127;
    u16* op = out + ((size_t)(b * 130 + oh + 1) * 130 + ow + 1) * 64;
    const u16* lp = lds + tid * 72;
    #pragma unroll
    for (int u = 0; u < 8; u++)
      *(uint4*)(op + u * 8) = *(const uint4*)(lp + u * 8);
  }
}

// ---------------- generic MFMA implicit-GEMM stride-2 4x4 conv (round-6 proven) ----------
// Prefetched K-slabs; 2-barrier K-loop; LDS-staged coalesced epilogue (32-px passes).
template<int CI, int CO, int HO, int WO, int OPAD, int WM, int WN, int FM, int FN>
__global__ __launch_bounds__(256, 2) void conv_mfma(const u16* __restrict__ in,
                                                    const u16* __restrict__ wr,
                                                    const float* __restrict__ bias,
                                                    u16* __restrict__ out){
  constexpr int HI  = 2 * HO + 2, WI = 2 * WO + 2;
  constexpr int HOP = HO + 2 * OPAD, WOP = WO + 2 * OPAD;
  constexpr int CC  = CI / 32;
  constexpr int LCC = ilog2c(CC);
  constexpr int NIT = 16 * CC;
  constexpr int TM  = WM * FM * 16, TN = WN * FN * 16;
  constexpr int ACH = TM / 64, BCH = TN / 64;
  constexpr int EPS = TN + 8;                 // epilogue LDS row stride (u16)
  constexpr int U4  = TN / 64;                // uint4 per thread per pass
  __shared__ __align__(16) u16 lds[(TM + TN) * 32];
  u16* ldsA = lds;
  u16* ldsB = lds + TM * 32;
  const int tid  = threadIdx.x;
  const int lane = tid & 63;
  const int w    = tid >> 6;
  const int quad = lane >> 4, l15 = lane & 15;
  const int wm = w & (WM - 1), wn = w >> ilog2c(WM);
  const int Mbase = blockIdx.x * TM;
  const int Nbase = blockIdx.y * TN;

  const int srow = tid >> 2;
  const int sel  = (tid & 3) * 8;
  int apix[ACH], brow[BCH];
  #pragma unroll
  for (int i = 0; i < ACH; i++){
    int p  = Mbase + srow + 64 * i;
    int b  = p / (HO * WO);
    int r  = p & (HO * WO - 1);
    int oh = r / WO, ow = r & (WO - 1);
    apix[i] = ((b * HI + 2 * oh) * WI + 2 * ow) * CI + sel;
  }
  #pragma unroll
  for (int i = 0; i < BCH; i++)
    brow[i] = (Nbase + srow + 64 * i) * CI + sel;

  f32x4 acc[FM][FN];
  #pragma unroll
  for (int i = 0; i < FM; i++)
    #pragma unroll
    for (int j = 0; j < FN; j++) acc[i][j] = (f32x4){0.f, 0.f, 0.f, 0.f};

  uint4 ra[ACH], rb[BCH];
  auto fetch = [&](int it){
    const int tap = it >> LCC, cc = it & (CC - 1);
    const int ad = ((tap >> 2) * WI + (tap & 3)) * CI + cc * 32;
    const int bd = tap * CO * CI + cc * 32;
    #pragma unroll
    for (int i = 0; i < ACH; i++) ra[i] = *(const uint4*)(in + apix[i] + ad);
    #pragma unroll
    for (int i = 0; i < BCH; i++) rb[i] = *(const uint4*)(wr + brow[i] + bd);
  };
  fetch(0);

  #pragma unroll 1
  for (int it = 0; it < NIT; ++it){
    __syncthreads();
    #pragma unroll
    for (int i = 0; i < ACH; i++)
      *(uint4*)(ldsA + (srow + 64 * i) * 32 + sel) = ra[i];
    #pragma unroll
    for (int i = 0; i < BCH; i++)
      *(uint4*)(ldsB + (srow + 64 * i) * 32 + sel) = rb[i];
    __syncthreads();
    if (it + 1 < NIT) fetch(it + 1);          // overlaps ds_read + MFMA below
    bf16x8 af[FM], bfr[FN];
    #pragma unroll
    for (int i = 0; i < FM; i++)
      af[i]  = *(const bf16x8*)(ldsA + ((wm * FM + i) * 16 + l15) * 32 + quad * 8);
    #pragma unroll
    for (int j = 0; j < FN; j++)
      bfr[j] = *(const bf16x8*)(ldsB + ((wn * FN + j) * 16 + l15) * 32 + quad * 8);
    #pragma unroll
    for (int i = 0; i < FM; i++)
      #pragma unroll
      for (int j = 0; j < FN; j++)
        acc[i][j] = __builtin_amdgcn_mfma_f32_16x16x32_bf16(af[i], bfr[j], acc[i][j], 0, 0, 0);
  }

  // epilogue: TM/32 passes of 32 pixels through LDS, coalesced uint4 stores
  float bv[FN];
  #pragma unroll
  for (int j = 0; j < FN; j++) bv[j] = bias[Nbase + (wn * FN + j) * 16 + l15];
  const int tpp = tid & 7, pp = tid >> 3;
  #pragma unroll 1
  for (int ps = 0; ps < TM / 32; ++ps){
    __syncthreads();
    #pragma unroll
    for (int i = 0; i < FM; i++){
      const int fr = wm * FM + i;
      if ((fr >> 1) == ps){
        const int lr0 = (fr & 1) * 16 + quad * 4;
        #pragma unroll
        for (int r = 0; r < 4; r++)
          #pragma unroll
          for (int j = 0; j < FN; j++)
            lds[(lr0 + r) * EPS + (wn * FN + j) * 16 + l15] =
                f2bf(fmaxf(acc[i][j][r] + bv[j], 0.f));
      }
    }
    __syncthreads();
    int gp = Mbase + ps * 32 + pp;
    int b  = gp / (HO * WO);
    int rr = gp & (HO * WO - 1);
    int oh = rr / WO, ow = rr & (WO - 1);
    u16* op = out + (((size_t)b * HOP + oh + OPAD) * WOP + ow + OPAD) * CO
                  + Nbase + tpp * (TN / 8);
    #pragma unroll
    for (int u = 0; u < U4; u++)
      *(uint4*)(op + u * 8) = *(const uint4*)(lds + pp * EPS + tpp * (TN / 8) + u * 8);
  }
}

// ---------------- pool ----------------
__global__ __launch_bounds__(512) void pool_k(const u16* __restrict__ act4,
                                              float* __restrict__ pooled){
  const int c = threadIdx.x;
  const int b = blockIdx.x;
  const u16* p = act4 + (size_t)b * 256 * 512 + c;
  float s = 0.f;
  for (int i = 0; i < 256; i++) s += bf2f(p[i * 512]);
  pooled[b * 512 + c] = s * (1.f / 256.f);
}

// ---------------- FC head ----------------
__global__ __launch_bounds__(64) void feat_k(const float* __restrict__ pooled,
                                             const float* __restrict__ hist,
                                             const float* __restrict__ wf, const float* __restrict__ bfv,
                                             const float* __restrict__ wh, const float* __restrict__ bh,
                                             const float* __restrict__ wo, const float* __restrict__ bo,
                                             float* __restrict__ cfeat){
  __shared__ float comb[128];
  const int j = threadIdx.x;
  const int b = blockIdx.x;
  const float* pb  = pooled + b * 512;
  const float* wfj = wf + j * 512;
  float s = bfv[j];
  for (int k = 0; k < 512; k++) s += pb[k] * wfj[k];
  comb[j] = s;
  const float* hb  = hist + b * 48;
  const float* whj = wh + j * 48;
  float t = bh[j];
  for (int k = 0; k < 48; k++) t += hb[k] * whj[k];
  comb[64 + j] = t;
  __syncthreads();
  if (j < 3){
    float c = bo[j];
    const float* woj = wo + j * 128;
    for (int k = 0; k < 128; k++) c += comb[k] * woj[k];
    cfeat[b * 3 + j] = c;
  }
}

// ---------------- broadcast ----------------
__global__ __launch_bounds__(256) void bcast_k(const float* __restrict__ cfeat,
                                               float* __restrict__ out){
  size_t i = (size_t)blockIdx.x * 256 + threadIdx.x;
  int bc = (int)(i >> 14);
  float v = cfeat[bc];
  ((float4*)out)[i] = make_float4(v, v, v, v);
}

extern "C" void kernel_launch(void* const* d_in, const int* in_sizes, int n_in,
                              void* d_out, int out_size, void* d_ws, size_t ws_size,
                              hipStream_t stream){
  const float* img = (const float*)d_in[0];
  const float* w1  = (const float*)d_in[1];
  const float* b1  = (const float*)d_in[2];
  const float* w2  = (const float*)d_in[3];
  const float* b2  = (const float*)d_in[4];
  const float* w3  = (const float*)d_in[5];
  const float* b3  = (const float*)d_in[6];
  const float* w4  = (const float*)d_in[7];
  const float* b4  = (const float*)d_in[8];
  const float* wf  = (const float*)d_in[9];
  const float* bfv = (const float*)d_in[10];
  const float* wh  = (const float*)d_in[11];
  const float* bh  = (const float*)d_in[12];
  const float* wo  = (const float*)d_in[13];
  const float* bo  = (const float*)d_in[14];
  float* out = (float*)d_out;
  (void)in_sizes; (void)n_in; (void)out_size; (void)ws_size;

  char* ws = (char*)d_ws;
  size_t off = 0;
  auto alloc = [&](size_t bytes) -> void* {
    void* p = ws + off;
    off += (bytes + 255) & ~(size_t)255;
    return p;
  };
  constexpr int BC = 16;
  const size_t A1c  = (size_t)BC * 130 * 130 * 64 * 2;    // 34.6 MB
  const size_t A2c  = (size_t)BC * 66 * 66 * 128 * 2;     // 17.8 MB
  const size_t A4   = (size_t)64 * 16 * 16 * 512 * 2;     // 16.8 MB

  u16*   slot = (u16*)alloc(A1c);
  u16*   act2 = (u16*)alloc(A2c);
  u16*   imgr = act2;                                     // alias
  u16*   act4 = (u16*)alloc(A4);
  u16*   w1m  = (u16*)  alloc((size_t)64 * 64 * 2);
  u16*   w2r  = (u16*)  alloc((size_t)16 * 128 * 64 * 2);
  u16*   w3r  = (u16*)  alloc((size_t)16 * 256 * 128 * 2);
  u16*   w4r  = (u16*)  alloc((size_t)16 * 512 * 256 * 2);
  float* raw    = (float*)alloc((size_t)192 * 16 * 4);
  float* hist   = (float*)alloc((size_t)192 * 16 * 4);
  float* pooled = (float*)alloc((size_t)64 * 512 * 4);
  float* cfeat  = (float*)alloc((size_t)64 * 3 * 4);

  repack_w1m <<<dim3(16),   256, 0, stream>>>(w1, w1m);
  repack_w_bf<<<dim3(512),  256, 0, stream>>>(w2, w2r, 64, 128);
  repack_w_bf<<<dim3(2048), 256, 0, stream>>>(w3, w3r, 128, 256);
  repack_w_bf<<<dim3(8192), 256, 0, stream>>>(w4, w4r, 256, 512);

  hipMemsetAsync(raw, 0, 192 * 16 * 4, stream);
  hist_part<<<dim3(192, 8), 256, 0, stream>>>(img, raw);
  hist_finish<<<dim3(12), 256, 0, stream>>>(raw, hist);

  const int nH1 = 16 * (2 * 130 * 32 + 128 * 2 * 32);
  const int nH2 = 16 * (2 * 66 * 64 + 64 * 2 * 64);
  const int nH3 = 16 * (2 * 34 * 128 + 32 * 2 * 128);
  const int nHI = 16 * (2 * 258 * 2 + 256 * 2 * 2);

  for (int c = 0; c < 4; ++c){
    const float* img_c  = img  + (size_t)c * BC * 3 * 65536;
    u16*         act4_c = act4 + (size_t)c * BC * 256 * 512;

    halo_zero<<<dim3((nHI + 255) / 256), 256, 0, stream>>>(imgr, 16, 258, 258, 4);
    repack_img<<<dim3(4096), 256, 0, stream>>>(img_c, imgr);
    halo_zero<<<dim3((nH1 + 255) / 256), 256, 0, stream>>>(slot, 16, 130, 130, 64);
    conv1_mfma<<<dim3(1024), 256, 0, stream>>>(imgr, w1m, b1, slot);
    halo_zero<<<dim3((nH2 + 255) / 256), 256, 0, stream>>>(act2, 16, 66, 66, 128);  // imgr dead
    // conv2: M=65536, 64x128 tiles -> 1024 blocks
    conv_mfma<64, 128, 64, 64, 1, 1, 4, 4, 2>
        <<<dim3(1024, 1), 256, 0, stream>>>(slot, w2r, b2, act2);
    halo_zero<<<dim3((nH3 + 255) / 256), 256, 0, stream>>>(slot, 16, 34, 34, 256);  // act1 dead
    // conv3: M=16384, 64x128 tiles -> grid(256,2)=512 blocks
    conv_mfma<128, 256, 32, 32, 1, 1, 4, 4, 2>
        <<<dim3(256, 2), 256, 0, stream>>>(act2, w3r, b3, slot);
    // conv4: M=4096, 64x64 tiles -> grid(64,8)=512 blocks
    conv_mfma<256, 512, 16, 16, 0, 2, 2, 2, 2>
        <<<dim3(64, 8), 256, 0, stream>>>(slot, w4r, b4, act4_c);
  }

  pool_k<<<dim3(64), 512, 0, stream>>>(act4, pooled);
  feat_k<<<dim3(64), 64, 0, stream>>>(pooled, hist, wf, bfv, wh, bh, wo, bo, cfeat);
  bcast_k<<<dim3(12288), 256, 0, stream>>>(cfeat, out);
}

// Round 11
// 794.740 us; speedup vs baseline: 1.8762x; 1.2764x over previous
//
// Round 11: (a) conv3 retiled TN=64 (was the real 74us top kernel — FETCH/WRITE
// signature matches conv3, not conv1; 512 blocks = 2/CU latency-bound);
// (b) ws_size-tiered full-batch conv3/conv4 (>=150MB: full act2 71MB, conv3
// @4096 blocks, conv4 @2048 blocks, one dispatch each; else round-10 chunked).
// Host-constant branch = graph-safe; no global_load_lds anywhere (round-2
// crash cause). conv_mfma template + conv1/hist/pool/head byte-identical.
// Predicted: full path 1014 -> ~650-750us; fallback ~950 w/ conv3 74->45.
#include <hip/hip_runtime.h>

typedef unsigned short u16;
typedef __attribute__((ext_vector_type(8))) short bf16x8;   // 8 bf16 (4 VGPRs)
typedef __attribute__((ext_vector_type(4))) float f32x4;

__device__ __forceinline__ float bf2f(u16 v){ return __uint_as_float(((unsigned)v) << 16); }
__device__ __forceinline__ u16 f2bf(float f){
  unsigned u = __float_as_uint(f);
  u += 0x7FFFu + ((u >> 16) & 1u);   // RNE
  return (u16)(u >> 16);
}

constexpr int ilog2c(int v){ return v <= 1 ? 0 : 1 + ilog2c(v / 2); }

// ---------------- weight repacks ----------------
__global__ __launch_bounds__(256) void repack_w1m(const float* __restrict__ src,
                                                  u16* __restrict__ dst){
  int i = blockIdx.x * 256 + threadIdx.x;     // over [64][64]
  if (i < 64 * 64){
    int k  = i & 63, co = i >> 6;
    int kh = k >> 4, kw = (k >> 2) & 3, ci = k & 3;
    float v = (ci < 3) ? src[((co * 3 + ci) * 4 + kh) * 4 + kw] : 0.f;
    dst[i] = f2bf(v);
  }
}
__global__ __launch_bounds__(256) void repack_w_bf(const float* __restrict__ src,
                                                   u16* __restrict__ dst,
                                                   int CI, int CO){
  int i = blockIdx.x * 256 + threadIdx.x;     // linear over src = [co][ci][16]
  if (i < CO * CI * 16){
    int t  = i & 15;
    int r  = i >> 4;
    int ci = r & (CI - 1);
    int co = r / CI;
    dst[((size_t)t * CO + co) * CI + ci] = f2bf(src[i]);
  }
}

// ---------------- img repack: NCHW fp32 (16 imgs) -> [16][258][258][4] bf16 ----------------
__global__ __launch_bounds__(256) void repack_img(const float* __restrict__ img,
                                                  u16* __restrict__ dst){
  int i = blockIdx.x * 256 + threadIdx.x;
  int b  = i >> 16;
  int r  = i & 65535;
  int ih = r >> 8, iw = r & 255;
  float c0 = img[((size_t)b * 3 + 0) * 65536 + r];
  float c1 = img[((size_t)b * 3 + 1) * 65536 + r];
  float c2 = img[((size_t)b * 3 + 2) * 65536 + r];
  ushort4 v = { f2bf(c0), f2bf(c1), f2bf(c2), 0 };
  *(ushort4*)(dst + ((size_t)(b * 258 + ih + 1) * 258 + iw + 1) * 4) = v;
}

// ---------------- halo ring zero ----------------
__global__ __launch_bounds__(256) void halo_zero(u16* __restrict__ buf,
                                                 int B, int H, int W, int C){
  const int C2 = C >> 1;
  const int rowCells = W * C2;
  const int colCells = (H - 2) * C2;
  const int perImg = 2 * rowCells + 2 * colCells;
  int i = blockIdx.x * 256 + threadIdx.x;
  if (i >= B * perImg) return;
  int b = i / perImg, r = i % perImg;
  int h, w, cx;
  if (r < 2 * rowCells){
    h = (r < rowCells) ? 0 : (H - 1);
    int rr = (r < rowCells) ? r : (r - rowCells);
    w = rr / C2; cx = rr % C2;
  } else {
    int rr = r - 2 * rowCells;
    int side = rr / colCells, r2 = rr % colCells;
    h = 1 + r2 / C2; w = side ? (W - 1) : 0; cx = r2 % C2;
  }
  ((unsigned*)buf)[(((size_t)b * H + h) * W + w) * C2 + cx] = 0u;
}

// ---------------- histogram ----------------
__global__ __launch_bounds__(256) void hist_part(const float* __restrict__ img,
                                                 float* __restrict__ raw){
  __shared__ float cnt[16 * 256];
  __shared__ float partial[16 * 17];
  const int tid = threadIdx.x;
  const int bc  = blockIdx.x;
  #pragma unroll
  for (int i = 0; i < 16; i++) cnt[i * 256 + tid] = 0.f;
  __syncthreads();
  const float4* p = (const float4*)(img + (size_t)bc * 65536 + blockIdx.y * 8192);
  #pragma unroll
  for (int it = 0; it < 8; ++it){
    float4 v = p[it * 256 + tid];
    float c[4] = { v.x, v.y, v.z, v.w };
    #pragma unroll
    for (int j = 0; j < 4; j++){
      float x = (c[j] + 1.f) * 0.5f;
      int idx = (int)floorf((x + 1.f) * 8.f);
      idx = min(max(idx, 0), 15);
      float inr = (x >= -1.f && x <= 1.f) ? 1.f : 0.f;
      cnt[idx * 256 + tid] += inr;
    }
  }
  __syncthreads();
  {
    int bin = tid & 15, g = tid >> 4;
    float s = 0.f;
    #pragma unroll
    for (int j = 0; j < 16; j++) s += cnt[bin * 256 + g * 16 + j];
    partial[bin * 17 + g] = s;
  }
  __syncthreads();
  if (tid < 16){
    float t = 0.f;
    #pragma unroll
    for (int g = 0; g < 16; g++) t += partial[tid * 17 + g];
    atomicAdd(raw + bc * 16 + tid, t);
  }
}
__global__ __launch_bounds__(256) void hist_finish(const float* __restrict__ raw,
                                                   float* __restrict__ hist){
  int i = blockIdx.x * 256 + threadIdx.x;
  if (i < 3072){
    const float* r = raw + (i >> 4) * 16;
    float s = 0.f;
    #pragma unroll
    for (int j = 0; j < 16; j++) s += r[j];
    hist[i] = r[i & 15] / (s + 1e-6f);
  }
}

// ---------------- conv1 MFMA, barrier-free K (CI=4 -> direct loads coalesced) -----------
__global__ __launch_bounds__(256, 2) void conv1_mfma(const u16* __restrict__ in,
                                                     const u16* __restrict__ wm1,  // [64][64]
                                                     const float* __restrict__ bias,
                                                     u16* __restrict__ out){
  __shared__ __align__(16) u16 lds[256 * 72];   // epilogue only (36 KB)
  const int tid  = threadIdx.x;
  const int lane = tid & 63;
  const int w    = tid >> 6;
  const int quad = lane >> 4, l15 = lane & 15;
  const int Mbase = blockIdx.x * 256;

  f32x4 acc[4][4];
  #pragma unroll
  for (int i = 0; i < 4; i++)
    #pragma unroll
    for (int j = 0; j < 4; j++) acc[i][j] = (f32x4){0.f, 0.f, 0.f, 0.f};

  bf16x8 bfr[2][4];
  #pragma unroll
  for (int cc = 0; cc < 2; cc++)
    #pragma unroll
    for (int j = 0; j < 4; j++)
      bfr[cc][j] = *(const bf16x8*)(wm1 + (j * 16 + l15) * 64 + cc * 32 + quad * 8);

  #pragma unroll
  for (int cc = 0; cc < 2; cc++){
    const int kh = cc * 2 + (quad >> 1), kw0 = (quad & 1) * 2;
    bf16x8 af[4];
    #pragma unroll
    for (int i = 0; i < 4; i++){
      int m  = Mbase + w * 64 + i * 16 + l15;
      int b  = m >> 14, rr = m & 16383;
      int oh = rr >> 7, ow = rr & 127;
      af[i] = *(const bf16x8*)(in + ((b * 258 + 2 * oh + kh) * 258 + 2 * ow + kw0) * 4);
    }
    #pragma unroll
    for (int i = 0; i < 4; i++)
      #pragma unroll
      for (int j = 0; j < 4; j++)
        acc[i][j] = __builtin_amdgcn_mfma_f32_16x16x32_bf16(af[i], bfr[cc][j], acc[i][j], 0, 0, 0);
  }

  float bv[4];
  #pragma unroll
  for (int j = 0; j < 4; j++) bv[j] = bias[j * 16 + l15];
  #pragma unroll
  for (int i = 0; i < 4; i++)
    #pragma unroll
    for (int r = 0; r < 4; r++){
      int row = w * 64 + i * 16 + quad * 4 + r;
      #pragma unroll
      for (int j = 0; j < 4; j++)
        lds[row * 72 + j * 16 + l15] = f2bf(fmaxf(acc[i][j][r] + bv[j], 0.f));
    }
  __syncthreads();
  {
    int m  = Mbase + tid;
    int b  = m >> 14, rr = m & 16383;
    int oh = rr >> 7, ow = rr & 127;
    u16* op = out + ((size_t)(b * 130 + oh + 1) * 130 + ow + 1) * 64;
    const u16* lp = lds + tid * 72;
    #pragma unroll
    for (int u = 0; u < 8; u++)
      *(uint4*)(op + u * 8) = *(const uint4*)(lp + u * 8);
  }
}

// ---------------- generic MFMA implicit-GEMM stride-2 4x4 conv (round-6 proven) ----------
template<int CI, int CO, int HO, int WO, int OPAD, int WM, int WN, int FM, int FN>
__global__ __launch_bounds__(256, 2) void conv_mfma(const u16* __restrict__ in,
                                                    const u16* __restrict__ wr,
                                                    const float* __restrict__ bias,
                                                    u16* __restrict__ out){
  constexpr int HI  = 2 * HO + 2, WI = 2 * WO + 2;
  constexpr int HOP = HO + 2 * OPAD, WOP = WO + 2 * OPAD;
  constexpr int CC  = CI / 32;
  constexpr int LCC = ilog2c(CC);
  constexpr int NIT = 16 * CC;
  constexpr int TM  = WM * FM * 16, TN = WN * FN * 16;
  constexpr int ACH = TM / 64, BCH = TN / 64;
  constexpr int EPS = TN + 8;                 // epilogue LDS row stride (u16)
  constexpr int U4  = TN / 64;                // uint4 per thread per pass
  __shared__ __align__(16) u16 lds[(TM + TN) * 32];
  u16* ldsA = lds;
  u16* ldsB = lds + TM * 32;
  const int tid  = threadIdx.x;
  const int lane = tid & 63;
  const int w    = tid >> 6;
  const int quad = lane >> 4, l15 = lane & 15;
  const int wm = w & (WM - 1), wn = w >> ilog2c(WM);
  const int Mbase = blockIdx.x * TM;
  const int Nbase = blockIdx.y * TN;

  const int srow = tid >> 2;
  const int sel  = (tid & 3) * 8;
  int apix[ACH], brow[BCH];
  #pragma unroll
  for (int i = 0; i < ACH; i++){
    int p  = Mbase + srow + 64 * i;
    int b  = p / (HO * WO);
    int r  = p & (HO * WO - 1);
    int oh = r / WO, ow = r & (WO - 1);
    apix[i] = ((b * HI + 2 * oh) * WI + 2 * ow) * CI + sel;
  }
  #pragma unroll
  for (int i = 0; i < BCH; i++)
    brow[i] = (Nbase + srow + 64 * i) * CI + sel;

  f32x4 acc[FM][FN];
  #pragma unroll
  for (int i = 0; i < FM; i++)
    #pragma unroll
    for (int j = 0; j < FN; j++) acc[i][j] = (f32x4){0.f, 0.f, 0.f, 0.f};

  uint4 ra[ACH], rb[BCH];
  auto fetch = [&](int it){
    const int tap = it >> LCC, cc = it & (CC - 1);
    const int ad = ((tap >> 2) * WI + (tap & 3)) * CI + cc * 32;
    const int bd = tap * CO * CI + cc * 32;
    #pragma unroll
    for (int i = 0; i < ACH; i++) ra[i] = *(const uint4*)(in + apix[i] + ad);
    #pragma unroll
    for (int i = 0; i < BCH; i++) rb[i] = *(const uint4*)(wr + brow[i] + bd);
  };
  fetch(0);

  #pragma unroll 1
  for (int it = 0; it < NIT; ++it){
    __syncthreads();
    #pragma unroll
    for (int i = 0; i < ACH; i++)
      *(uint4*)(ldsA + (srow + 64 * i) * 32 + sel) = ra[i];
    #pragma unroll
    for (int i = 0; i < BCH; i++)
      *(uint4*)(ldsB + (srow + 64 * i) * 32 + sel) = rb[i];
    __syncthreads();
    if (it + 1 < NIT) fetch(it + 1);          // overlaps ds_read + MFMA below
    bf16x8 af[FM], bfr[FN];
    #pragma unroll
    for (int i = 0; i < FM; i++)
      af[i]  = *(const bf16x8*)(ldsA + ((wm * FM + i) * 16 + l15) * 32 + quad * 8);
    #pragma unroll
    for (int j = 0; j < FN; j++)
      bfr[j] = *(const bf16x8*)(ldsB + ((wn * FN + j) * 16 + l15) * 32 + quad * 8);
    #pragma unroll
    for (int i = 0; i < FM; i++)
      #pragma unroll
      for (int j = 0; j < FN; j++)
        acc[i][j] = __builtin_amdgcn_mfma_f32_16x16x32_bf16(af[i], bfr[j], acc[i][j], 0, 0, 0);
  }

  // epilogue: TM/32 passes of 32 pixels through LDS, coalesced uint4 stores
  float bv[FN];
  #pragma unroll
  for (int j = 0; j < FN; j++) bv[j] = bias[Nbase + (wn * FN + j) * 16 + l15];
  const int tpp = tid & 7, pp = tid >> 3;
  #pragma unroll 1
  for (int ps = 0; ps < TM / 32; ++ps){
    __syncthreads();
    #pragma unroll
    for (int i = 0; i < FM; i++){
      const int fr = wm * FM + i;
      if ((fr >> 1) == ps){
        const int lr0 = (fr & 1) * 16 + quad * 4;
        #pragma unroll
        for (int r = 0; r < 4; r++)
          #pragma unroll
          for (int j = 0; j < FN; j++)
            lds[(lr0 + r) * EPS + (wn * FN + j) * 16 + l15] =
                f2bf(fmaxf(acc[i][j][r] + bv[j], 0.f));
      }
    }
    __syncthreads();
    int gp = Mbase + ps * 32 + pp;
    int b  = gp / (HO * WO);
    int rr = gp & (HO * WO - 1);
    int oh = rr / WO, ow = rr & (WO - 1);
    u16* op = out + (((size_t)b * HOP + oh + OPAD) * WOP + ow + OPAD) * CO
                  + Nbase + tpp * (TN / 8);
    #pragma unroll
    for (int u = 0; u < U4; u++)
      *(uint4*)(op + u * 8) = *(const uint4*)(lds + pp * EPS + tpp * (TN / 8) + u * 8);
  }
}

// ---------------- pool ----------------
__global__ __launch_bounds__(512) void pool_k(const u16* __restrict__ act4,
                                              float* __restrict__ pooled){
  const int c = threadIdx.x;
  const int b = blockIdx.x;
  const u16* p = act4 + (size_t)b * 256 * 512 + c;
  float s = 0.f;
  for (int i = 0; i < 256; i++) s += bf2f(p[i * 512]);
  pooled[b * 512 + c] = s * (1.f / 256.f);
}

// ---------------- FC head ----------------
__global__ __launch_bounds__(64) void feat_k(const float* __restrict__ pooled,
                                             const float* __restrict__ hist,
                                             const float* __restrict__ wf, const float* __restrict__ bfv,
                                             const float* __restrict__ wh, const float* __restrict__ bh,
                                             const float* __restrict__ wo, const float* __restrict__ bo,
                                             float* __restrict__ cfeat){
  __shared__ float comb[128];
  const int j = threadIdx.x;
  const int b = blockIdx.x;
  const float* pb  = pooled + b * 512;
  const float* wfj = wf + j * 512;
  float s = bfv[j];
  for (int k = 0; k < 512; k++) s += pb[k] * wfj[k];
  comb[j] = s;
  const float* hb  = hist + b * 48;
  const float* whj = wh + j * 48;
  float t = bh[j];
  for (int k = 0; k < 48; k++) t += hb[k] * whj[k];
  comb[64 + j] = t;
  __syncthreads();
  if (j < 3){
    float c = bo[j];
    const float* woj = wo + j * 128;
    for (int k = 0; k < 128; k++) c += comb[k] * woj[k];
    cfeat[b * 3 + j] = c;
  }
}

// ---------------- broadcast ----------------
__global__ __launch_bounds__(256) void bcast_k(const float* __restrict__ cfeat,
                                               float* __restrict__ out){
  size_t i = (size_t)blockIdx.x * 256 + threadIdx.x;
  int bc = (int)(i >> 14);
  float v = cfeat[bc];
  ((float4*)out)[i] = make_float4(v, v, v, v);
}

extern "C" void kernel_launch(void* const* d_in, const int* in_sizes, int n_in,
                              void* d_out, int out_size, void* d_ws, size_t ws_size,
                              hipStream_t stream){
  const float* img = (const float*)d_in[0];
  const float* w1  = (const float*)d_in[1];
  const float* b1  = (const float*)d_in[2];
  const float* w2  = (const float*)d_in[3];
  const float* b2  = (const float*)d_in[4];
  const float* w3  = (const float*)d_in[5];
  const float* b3  = (const float*)d_in[6];
  const float* w4  = (const float*)d_in[7];
  const float* b4  = (const float*)d_in[8];
  const float* wf  = (const float*)d_in[9];
  const float* bfv = (const float*)d_in[10];
  const float* wh  = (const float*)d_in[11];
  const float* bh  = (const float*)d_in[12];
  const float* wo  = (const float*)d_in[13];
  const float* bo  = (const float*)d_in[14];
  float* out = (float*)d_out;
  (void)in_sizes; (void)n_in; (void)out_size;

  char* ws = (char*)d_ws;
  size_t off = 0;
  auto alloc = [&](size_t bytes) -> void* {
    void* p = ws + off;
    off += (bytes + 255) & ~(size_t)255;
    return p;
  };
  constexpr int BC = 16;
  const size_t A1c = (size_t)BC * 130 * 130 * 64 * 2;     // 34.6 MB
  const size_t A2c = (size_t)BC * 66 * 66 * 128 * 2;      // 17.8 MB
  const size_t A2f = (size_t)64 * 66 * 66 * 128 * 2;      // 71.4 MB
  const size_t A3f = (size_t)64 * 34 * 34 * 256 * 2;      // 37.9 MB
  const size_t A4  = (size_t)64 * 16 * 16 * 512 * 2;      // 16.8 MB
  const size_t IMG = (size_t)BC * 258 * 258 * 4 * 2;      //  8.5 MB

  // common small buffers first (~5.5 MB)
  u16*   w1m  = (u16*)  alloc((size_t)64 * 64 * 2);
  u16*   w2r  = (u16*)  alloc((size_t)16 * 128 * 64 * 2);
  u16*   w3r  = (u16*)  alloc((size_t)16 * 256 * 128 * 2);
  u16*   w4r  = (u16*)  alloc((size_t)16 * 512 * 256 * 2);
  float* raw    = (float*)alloc((size_t)192 * 16 * 4);
  float* hist   = (float*)alloc((size_t)192 * 16 * 4);
  float* pooled = (float*)alloc((size_t)64 * 512 * 4);
  float* cfeat  = (float*)alloc((size_t)64 * 3 * 4);

  const bool full = ws_size >= (150ull << 20);   // host-constant -> graph-safe

  repack_w1m <<<dim3(16),   256, 0, stream>>>(w1, w1m);
  repack_w_bf<<<dim3(512),  256, 0, stream>>>(w2, w2r, 64, 128);
  repack_w_bf<<<dim3(2048), 256, 0, stream>>>(w3, w3r, 128, 256);
  repack_w_bf<<<dim3(8192), 256, 0, stream>>>(w4, w4r, 256, 512);

  hipMemsetAsync(raw, 0, 192 * 16 * 4, stream);
  hist_part<<<dim3(192, 8), 256, 0, stream>>>(img, raw);
  hist_finish<<<dim3(12), 256, 0, stream>>>(raw, hist);

  // halo u32 cell counts
  const int nH1  = 16 * (2 * 130 * 32 + 128 * 2 * 32);
  const int nH2c = 16 * (2 * 66 * 64 + 64 * 2 * 64);
  const int nH2f = 64 * (2 * 66 * 64 + 64 * 2 * 64);
  const int nH3c = 16 * (2 * 34 * 128 + 32 * 2 * 128);
  const int nH3f = 64 * (2 * 34 * 128 + 32 * 2 * 128);
  const int nHI  = 16 * (2 * 258 * 2 + 256 * 2 * 2);

  if (full){
    // ---- full-batch conv3/conv4 path (~140 MB) ----
    u16* slotU = (u16*)alloc(A3f);   // act1c (34.6) / act3 full (37.9) union
    u16* act2f = (u16*)alloc(A2f);
    u16* imgr  = (u16*)alloc(IMG);
    u16* act4  = (u16*)alloc(A4);

    halo_zero<<<dim3((nHI  + 255) / 256), 256, 0, stream>>>(imgr, 16, 258, 258, 4);
    halo_zero<<<dim3((nH1  + 255) / 256), 256, 0, stream>>>(slotU, 16, 130, 130, 64);
    halo_zero<<<dim3((nH2f + 255) / 256), 256, 0, stream>>>(act2f, 64, 66, 66, 128);
    for (int c = 0; c < 4; ++c){
      const float* img_c = img + (size_t)c * BC * 3 * 65536;
      repack_img<<<dim3(4096), 256, 0, stream>>>(img_c, imgr);
      conv1_mfma<<<dim3(1024), 256, 0, stream>>>(imgr, w1m, b1, slotU);
      conv_mfma<64, 128, 64, 64, 1, 1, 4, 4, 2>
          <<<dim3(1024, 1), 256, 0, stream>>>(slotU, w2r, b2,
                                              act2f + (size_t)c * BC * 66 * 66 * 128);
    }
    halo_zero<<<dim3((nH3f + 255) / 256), 256, 0, stream>>>(slotU, 64, 34, 34, 256);
    // conv3 full: M=65536, 64x64 tiles -> grid(1024,4)=4096 blocks
    conv_mfma<128, 256, 32, 32, 1, 2, 2, 2, 2>
        <<<dim3(1024, 4), 256, 0, stream>>>(act2f, w3r, b3, slotU);
    // conv4 full: M=16384, 64x64 tiles -> grid(256,8)=2048 blocks
    conv_mfma<256, 512, 16, 16, 0, 2, 2, 2, 2>
        <<<dim3(256, 8), 256, 0, stream>>>(slotU, w4r, b4, act4);

    pool_k<<<dim3(64), 512, 0, stream>>>(act4, pooled);
  } else {
    // ---- proven chunked path (~81 MB) ----
    u16* slot = (u16*)alloc(A1c);
    u16* act2 = (u16*)alloc(A2c);
    u16* imgr = act2;                // alias
    u16* act4 = (u16*)alloc(A4);

    for (int c = 0; c < 4; ++c){
      const float* img_c  = img  + (size_t)c * BC * 3 * 65536;
      u16*         act4_c = act4 + (size_t)c * BC * 256 * 512;

      halo_zero<<<dim3((nHI  + 255) / 256), 256, 0, stream>>>(imgr, 16, 258, 258, 4);
      repack_img<<<dim3(4096), 256, 0, stream>>>(img_c, imgr);
      halo_zero<<<dim3((nH1  + 255) / 256), 256, 0, stream>>>(slot, 16, 130, 130, 64);
      conv1_mfma<<<dim3(1024), 256, 0, stream>>>(imgr, w1m, b1, slot);
      halo_zero<<<dim3((nH2c + 255) / 256), 256, 0, stream>>>(act2, 16, 66, 66, 128);
      conv_mfma<64, 128, 64, 64, 1, 1, 4, 4, 2>
          <<<dim3(1024, 1), 256, 0, stream>>>(slot, w2r, b2, act2);
      halo_zero<<<dim3((nH3c + 255) / 256), 256, 0, stream>>>(slot, 16, 34, 34, 256);
      // conv3: 64x64 tiles -> grid(256,4)=1024 blocks (was 512)
      conv_mfma<128, 256, 32, 32, 1, 2, 2, 2, 2>
          <<<dim3(256, 4), 256, 0, stream>>>(act2, w3r, b3, slot);
      conv_mfma<256, 512, 16, 16, 0, 2, 2, 2, 2>
          <<<dim3(64, 8), 256, 0, stream>>>(slot, w4r, b4, act4_c);
    }
    pool_k<<<dim3(64), 512, 0, stream>>>(act4, pooled);
  }

  feat_k<<<dim3(64), 64, 0, stream>>>(pooled, hist, wf, bfv, wh, bh, wo, bo, cfeat);
  bcast_k<<<dim3(12288), 256, 0, stream>>>(cfeat, out);
}